// Round 4
// baseline (561.714 us; speedup 1.0000x reference)
//
#include <hip/hip_runtime.h>
#include <stdint.h>

#define HIDDEN 1024
#define INTER  4096
#define NTOK   4096
#define HROWS  (2*NTOK)
#define MAXB1  40            // 256-row-granularity table (mlp1)
#define MAXB2  72            // 128-row-granularity table (mlp2)
#define NMAT   27            // 0..8: w1s,W1[0..7]; 9..17: w2s,W2; 18..26: w3s,W3

typedef unsigned short u16;
typedef unsigned int   u32;
typedef __bf16  bf16x8 __attribute__((ext_vector_type(8)));
typedef float   f32x4  __attribute__((ext_vector_type(4)));
typedef u32     u32x4  __attribute__((ext_vector_type(4)));

#define WAITVM(N) asm volatile("s_waitcnt vmcnt(" #N ")" ::: "memory")

__device__ __forceinline__ void hard_barrier() {
  asm volatile("" ::: "memory");
  __builtin_amdgcn_s_barrier();
  asm volatile("" ::: "memory");
}

__device__ __forceinline__ u16 f2bf(float f) {
  u32 u = __float_as_uint(f);
  u32 r = u + 0x7FFFu + ((u >> 16) & 1u);
  return (u16)(r >> 16);
}

__device__ __forceinline__ u32 cvt_pk_bf16(float lo, float hi) {
  u32 r;
  asm("v_cvt_pk_bf16_f32 %0, %1, %2" : "=v"(r) : "v"(lo), "v"(hi));
  return r;
}

__device__ __forceinline__ void glds16(const void* g, void* l) {
  __builtin_amdgcn_global_load_lds(
      (const __attribute__((address_space(1))) void*)g,
      (__attribute__((address_space(3))) void*)l, 16, 0, 0);
}

// ---------------- routing ----------------

__global__ void k_init(int* cnt, int* fill) {
  if (threadIdx.x < 8) { cnt[threadIdx.x] = 0; fill[threadIdx.x] = 0; }
}

__global__ __launch_bounds__(256) void k_gate(const float* __restrict__ x,
                                              const float* __restrict__ wg,
                                              int* __restrict__ idx,
                                              int* __restrict__ cnt) {
  int wave = threadIdx.x >> 6, lane = threadIdx.x & 63;
  int t = blockIdx.x * 4 + wave;
  if (t >= NTOK) return;
  float acc[8];
  #pragma unroll
  for (int e = 0; e < 8; ++e) acc[e] = 0.f;
  const float* xr = x + (size_t)t * HIDDEN;
  for (int c = lane; c < HIDDEN; c += 64) {
    float xv = xr[c];
    const float* wrow = wg + (size_t)c * 8;
    #pragma unroll
    for (int e = 0; e < 8; ++e) acc[e] += xv * wrow[e];
  }
  #pragma unroll
  for (int e = 0; e < 8; ++e)
    for (int s = 32; s; s >>= 1) acc[e] += __shfl_xor(acc[e], s);
  if (lane == 0) {
    int best = 0; float bv = acc[0];
    #pragma unroll
    for (int e = 1; e < 8; ++e) if (acc[e] > bv) { bv = acc[e]; best = e; }
    idx[t] = best;
    atomicAdd(&cnt[best], 1);
  }
}

__global__ void k_cvt(const float* __restrict__ x, u16* __restrict__ xb, int n4) {
  int i = blockIdx.x * blockDim.x + threadIdx.x;
  if (i >= n4) return;
  float4 v = ((const float4*)x)[i];
  ushort4 o;
  o.x = f2bf(v.x); o.y = f2bf(v.y); o.z = f2bf(v.z); o.w = f2bf(v.w);
  ((ushort4*)xb)[i] = o;
}

__global__ void k_table(const int* __restrict__ cnt, int* __restrict__ off,
                        int4* __restrict__ tab1, int* __restrict__ nblk1,
                        int4* __restrict__ tab2, int* __restrict__ nblk2) {
  if (threadIdx.x != 0 || blockIdx.x != 0) return;
  int o = 0;
  int offs[8];
  for (int e = 0; e < 8; ++e) { offs[e] = o; off[e] = o; o += cnt[e]; }
  int nb = 0;
  for (int m = 0; m < NTOK / 256; ++m)
    tab1[nb++] = make_int4(8, m * 256, 256, 0);
  for (int e = 0; e < 8; ++e)
    for (int j = 0; j * 256 < cnt[e]; ++j) {
      int rows = cnt[e] - j * 256; if (rows > 256) rows = 256;
      tab1[nb++] = make_int4(e, NTOK + offs[e] + j * 256, rows, offs[e] + j * 256);
    }
  *nblk1 = nb;
  nb = 0;
  for (int m = 0; m < NTOK / 128; ++m)
    tab2[nb++] = make_int4(8, m * 128, 128, 0);
  for (int e = 0; e < 8; ++e)
    for (int j = 0; j * 128 < cnt[e]; ++j) {
      int rows = cnt[e] - j * 128; if (rows > 128) rows = 128;
      tab2[nb++] = make_int4(e, NTOK + offs[e] + j * 128, rows, offs[e] + j * 128);
    }
  *nblk2 = nb;
}

__global__ void k_scatter(const int* __restrict__ idx, const int* __restrict__ off,
                          int* __restrict__ fill, int* __restrict__ perm) {
  int t = blockIdx.x * blockDim.x + threadIdx.x;
  if (t >= NTOK) return;
  int e = idx[t];
  int p = atomicAdd(&fill[e], 1);
  perm[off[e] + p] = t;
}

// ---------------- weight precvt: fp32 [K][N] -> bf16 pre-swizzled 8KB BK=32 panels ----------------
// Panel (matrix m, kt, pp): [128 n][32 k] bf16; u16 offset n*32 + s*8 + (k&7),
// slot s holds k-chunk (s ^ ((n>>1)&3)).  panelIdx = m*1024 + kt*Tp + pp
// (w1/w2: Tp=32; w3: Tp=8).  One block converts 2 adjacent panels (256 cols).

__global__ __launch_bounds__(256) void k_wcvt(
    const float* __restrict__ w1s, const float* __restrict__ w2s,
    const float* __restrict__ w3s, const float* __restrict__ W1,
    const float* __restrict__ W2,  const float* __restrict__ W3,
    u16* __restrict__ Wb)
{
  int bid = blockIdx.x;            // 0 .. 27*512-1
  int m = bid >> 9, pair = bid & 511;
  const float* src; int N, Tp, kt, pp2;
  if (m < 18) {
    N = INTER; Tp = 32;
    int mm = (m < 9) ? m : m - 9;
    const float* sp = (m < 9) ? w1s : w2s;
    const float* ep = (m < 9) ? W1 : W2;
    src = (mm == 0) ? sp : ep + (size_t)(mm - 1) * HIDDEN * INTER;
    kt = pair >> 4; pp2 = pair & 15;
  } else {
    N = HIDDEN; Tp = 8;
    int mm = m - 18;
    src = (mm == 0) ? w3s : W3 + (size_t)(mm - 1) * INTER * HIDDEN;
    kt = pair >> 2; pp2 = pair & 3;
  }

  __shared__ float tileF[32 * 256];
  int tid = threadIdx.x;
  const float* in0 = src + (size_t)(kt * 32) * N + pp2 * 256;
  #pragma unroll
  for (int i = 0; i < 8; ++i) {
    int f = tid + 256 * i;          // float4 index within 32x256 tile
    int k = f >> 6, c4 = f & 63;
    *(float4*)&tileF[k * 256 + c4 * 4] = *(const float4*)(in0 + (size_t)k * N + c4 * 4);
  }
  __syncthreads();

  int p2 = tid >> 7, n = tid & 127;
  u16* outp = Wb + ((size_t)m * 1024 + kt * Tp + pp2 * 2 + p2) * 4096 + n * 32;
  #pragma unroll
  for (int s = 0; s < 4; ++s) {
    int k8 = s ^ ((n >> 1) & 3);
    const float* col = &tileF[(k8 * 8) * 256 + p2 * 128 + n];
    u32x4 pk;
    pk.x = cvt_pk_bf16(col[0],    col[256]);
    pk.y = cvt_pk_bf16(col[512],  col[768]);
    pk.z = cvt_pk_bf16(col[1024], col[1280]);
    pk.w = cvt_pk_bf16(col[1536], col[1792]);
    *(u32x4*)(outp + s * 8) = pk;
  }
}

// ---------------- stage 1: H = gelu(Xg@W1) * (Xg@W2) ----------------
// 256x(128 dual) tile, 8 waves (2M x 4N), BK=32, 4-buffer counted-vmcnt pipeline.
// Per buffer (32KB): A [0,16384), B1 [16384,24576), B2 [24576,32768).

__global__ __launch_bounds__(512, 2) void k_mlp1(
    const u16* __restrict__ xb, const u16* __restrict__ Wb,
    const int* __restrict__ perm, const int4* __restrict__ tab,
    const int* __restrict__ nblk, u16* __restrict__ Hbuf)
{
  int bx = blockIdx.x;
  if (bx >= *nblk) return;
  int4 te = tab[bx];
  int g = te.x, hrow0 = te.y, rows = te.z, pb = te.w;
  int m1 = (g == 8) ? 0 : 1 + g;
  int pp = blockIdx.y;
  int nbase = pp * 128;

  extern __shared__ __align__(16) char smem[];
  int tid = threadIdx.x;
  int w = tid >> 6, lane = tid & 63;
  int q = lane >> 4, rl = lane & 15;
  int mw = w >> 2, nw = w & 3;

  int tokj[2];
  #pragma unroll
  for (int j = 0; j < 2; ++j) {
    int r = w * 32 + j * 16 + (lane >> 2);
    int rc = (r < rows) ? r : (rows - 1);
    tokj[j] = (g == 8) ? (hrow0 + rc) : perm[pb + rc];
  }
  int gch = ((lane & 3) ^ ((lane >> 3) & 3)) * 16;   // source chunk byte offset

  const char* pB1 = (const char*)Wb + ((size_t)m1 * 1024 + pp) * 8192;
  const char* pB2 = (const char*)Wb + ((size_t)(m1 + 9) * 1024 + pp) * 8192;

  f32x4 acc1[8][2], acc2[8][2];
  f32x4 z = {0.f, 0.f, 0.f, 0.f};
  #pragma unroll
  for (int mi = 0; mi < 8; ++mi)
    #pragma unroll
    for (int ni = 0; ni < 2; ++ni) { acc1[mi][ni] = z; acc2[mi][ni] = z; }

  auto STAGE = [&](int t) {
    char* L = smem + (t & 3) * 32768;
    int k0 = t * 32;
    #pragma unroll
    for (int j = 0; j < 2; ++j) {
      const char* src = (const char*)xb + ((size_t)tokj[j] * HIDDEN + k0) * 2 + gch;
      glds16(src, L + w * 2048 + j * 1024);
    }
    glds16(pB1 + (size_t)t * 262144 + (tid << 4), L + 16384 + w * 1024);
    glds16(pB2 + (size_t)t * 262144 + (tid << 4), L + 24576 + w * 1024);
  };

  int co = (q ^ ((rl >> 1) & 3)) * 8;

  auto COMPUTE = [&](int t) {
    const u16* LA  = (const u16*)(smem + (t & 3) * 32768);
    const u16* LB1 = LA + 8192;
    const u16* LB2 = LA + 12288;
    bf16x8 af[8], b1[2], b2[2];
    #pragma unroll
    for (int mi = 0; mi < 8; ++mi)
      af[mi] = *(const bf16x8*)&LA[(mw * 128 + mi * 16 + rl) * 32 + co];
    #pragma unroll
    for (int ni = 0; ni < 2; ++ni) {
      int n = nw * 32 + ni * 16 + rl;
      b1[ni] = *(const bf16x8*)&LB1[n * 32 + co];
      b2[ni] = *(const bf16x8*)&LB2[n * 32 + co];
    }
    __builtin_amdgcn_s_setprio(1);
    #pragma unroll
    for (int mi = 0; mi < 8; ++mi)
      #pragma unroll
      for (int ni = 0; ni < 2; ++ni) {
        acc1[mi][ni] = __builtin_amdgcn_mfma_f32_16x16x32_bf16(af[mi], b1[ni], acc1[mi][ni], 0, 0, 0);
        acc2[mi][ni] = __builtin_amdgcn_mfma_f32_16x16x32_bf16(af[mi], b2[ni], acc2[mi][ni], 0, 0, 0);
      }
    __builtin_amdgcn_s_setprio(0);
  };

  const int NT = HIDDEN / 32;
  STAGE(0); STAGE(1); STAGE(2);
  for (int t = 0; t < NT; ++t) {
    if (t + 3 < NT) STAGE(t + 3);
    int rem = NT - 1 - t;
    if (rem >= 3)      WAITVM(12);
    else if (rem == 2) WAITVM(8);
    else if (rem == 1) WAITVM(4);
    else               WAITVM(0);
    hard_barrier();
    COMPUTE(t);
    hard_barrier();
  }

  #pragma unroll
  for (int mi = 0; mi < 8; ++mi) {
    #pragma unroll
    for (int j = 0; j < 4; ++j) {
      int r = mw * 128 + mi * 16 + q * 4 + j;
      if (r < rows) {
        size_t hb = (size_t)(hrow0 + r) * INTER + nbase + nw * 32;
        #pragma unroll
        for (int ni = 0; ni < 2; ++ni) {
          float h1 = acc1[mi][ni][j];
          float h2 = acc2[mi][ni][j];
          float ge = 0.5f * h1 * (1.0f + erff(h1 * 0.7071067811865476f));
          Hbuf[hb + ni * 16 + rl] = f2bf(ge * h2);
        }
      }
    }
  }
}

// ---------------- stage 2: Y = H @ W3 ----------------
// 128x256 tile, 8 waves (2M x 4N), BK=32, 4-buffer counted-vmcnt pipeline.
// Per buffer (24KB): A [0,8192), B [8192,24576) (two 8KB panels concat).

__global__ __launch_bounds__(512, 2) void k_mlp2(
    const u16* __restrict__ Hbuf, const u16* __restrict__ Wb,
    const int* __restrict__ perm, const int4* __restrict__ tab,
    const int* __restrict__ nblk, float* __restrict__ out,
    float* __restrict__ yexp)
{
  int bx = blockIdx.x;
  if (bx >= *nblk) return;
  int4 te = tab[bx];
  int g = te.x, hrow0 = te.y, rows = te.z, pb = te.w;
  int m3 = (g == 8) ? 18 : 19 + g;
  int pp2 = blockIdx.y;

  extern __shared__ __align__(16) char smem[];
  int tid = threadIdx.x;
  int w = tid >> 6, lane = tid & 63;
  int q = lane >> 4, rl = lane & 15;
  int mw = w >> 2, nw = w & 3;

  int rr = w * 16 + (lane >> 2);
  int rc = (rr < rows) ? rr : (rows - 1);
  int hr = hrow0 + rc;
  int gch = ((lane & 3) ^ ((lane >> 3) & 3)) * 16;

  const char* pB = (const char*)Wb + ((size_t)m3 * 1024 + pp2 * 2) * 8192;

  f32x4 acc[4][4];
  f32x4 z = {0.f, 0.f, 0.f, 0.f};
  #pragma unroll
  for (int mi = 0; mi < 4; ++mi)
    #pragma unroll
    for (int ni = 0; ni < 4; ++ni) acc[mi][ni] = z;

  auto STAGE = [&](int t) {
    char* L = smem + (t & 3) * 24576;
    int k0 = t * 32;
    const char* src = (const char*)Hbuf + ((size_t)hr * INTER + k0) * 2 + gch;
    glds16(src, L + w * 1024);
    #pragma unroll
    for (int j = 0; j < 2; ++j)
      glds16(pB + (size_t)t * 65536 + j * 8192 + (tid << 4), L + 8192 + j * 8192 + w * 1024);
  };

  int co = (q ^ ((rl >> 1) & 3)) * 8;

  auto COMPUTE = [&](int t) {
    const u16* LA = (const u16*)(smem + (t & 3) * 24576);
    const u16* LB = LA + 4096;
    bf16x8 af[4], bf[4];
    #pragma unroll
    for (int mi = 0; mi < 4; ++mi)
      af[mi] = *(const bf16x8*)&LA[(mw * 64 + mi * 16 + rl) * 32 + co];
    #pragma unroll
    for (int ni = 0; ni < 4; ++ni) {
      int n = nw * 64 + ni * 16 + rl;
      bf[ni] = *(const bf16x8*)&LB[n * 32 + co];
    }
    __builtin_amdgcn_s_setprio(1);
    #pragma unroll
    for (int mi = 0; mi < 4; ++mi)
      #pragma unroll
      for (int ni = 0; ni < 4; ++ni)
        acc[mi][ni] = __builtin_amdgcn_mfma_f32_16x16x32_bf16(af[mi], bf[ni], acc[mi][ni], 0, 0, 0);
    __builtin_amdgcn_s_setprio(0);
  };

  const int NT = INTER / 32;
  STAGE(0); STAGE(1); STAGE(2);
  for (int t = 0; t < NT; ++t) {
    if (t + 3 < NT) STAGE(t + 3);
    int rem = NT - 1 - t;
    if (rem >= 3)      WAITVM(9);
    else if (rem == 2) WAITVM(6);
    else if (rem == 1) WAITVM(3);
    else               WAITVM(0);
    hard_barrier();
    COMPUTE(t);
    hard_barrier();
  }

  float* dstb = (g == 8) ? out : yexp;
  #pragma unroll
  for (int mi = 0; mi < 4; ++mi) {
    #pragma unroll
    for (int j = 0; j < 4; ++j) {
      int r = mw * 64 + mi * 16 + q * 4 + j;
      if (r < rows) {
        int tok = (g == 8) ? (hrow0 + r) : perm[pb + r];
        size_t ob = (size_t)tok * HIDDEN + pp2 * 256 + nw * 64;
        #pragma unroll
        for (int ni = 0; ni < 4; ++ni)
          dstb[ob + ni * 16 + rl] = acc[mi][ni][j];
      }
    }
  }
}

__global__ void k_add(float* __restrict__ out, const float* __restrict__ yexp, int n4) {
  int i = blockIdx.x * blockDim.x + threadIdx.x;
  if (i >= n4) return;
  float4 a = ((const float4*)out)[i];
  float4 b = ((const float4*)yexp)[i];
  a.x += b.x; a.y += b.y; a.z += b.z; a.w += b.w;
  ((float4*)out)[i] = a;
}

// ---------------- launcher ----------------

extern "C" void kernel_launch(void* const* d_in, const int* in_sizes, int n_in,
                              void* d_out, int out_size, void* d_ws, size_t ws_size,
                              hipStream_t stream) {
  const float* x   = (const float*)d_in[0];
  const float* w1s = (const float*)d_in[1];
  const float* w2s = (const float*)d_in[2];
  const float* w3s = (const float*)d_in[3];
  const float* W1  = (const float*)d_in[4];
  const float* W2  = (const float*)d_in[5];
  const float* W3  = (const float*)d_in[6];
  const float* Wg  = (const float*)d_in[7];
  float* out = (float*)d_out;

  char* ws = (char*)d_ws;
  size_t o_xb   = 0;
  size_t o_H    = o_xb   + (size_t)NTOK * HIDDEN * 2;           // 8 MB
  size_t o_yexp = o_H    + (size_t)HROWS * INTER * 2;           // +64 MB
  size_t o_Wb   = o_yexp + (size_t)NTOK * HIDDEN * 4;           // +16 MB
  size_t o_idx  = o_Wb   + (size_t)NMAT * 1024 * 8192;          // +216 MB
  size_t o_perm = o_idx  + (size_t)NTOK * 4;
  size_t o_cnt  = o_perm + (size_t)NTOK * 4;
  size_t o_off  = o_cnt  + 32;
  size_t o_fill = o_off  + 32;
  size_t o_nb1  = o_fill + 32;
  size_t o_nb2  = o_nb1  + 32;
  size_t o_tab1 = o_nb2  + 32;
  size_t o_tab2 = o_tab1 + (size_t)MAXB1 * 16;
  size_t need   = o_tab2 + (size_t)MAXB2 * 16;
  if (ws_size < need) return;  // insufficient scratch

  u16*  xb   = (u16*)(ws + o_xb);
  u16*  Hbuf = (u16*)(ws + o_H);
  float* yexp = (float*)(ws + o_yexp);
  u16*  Wb   = (u16*)(ws + o_Wb);
  int*  idx  = (int*)(ws + o_idx);
  int*  perm = (int*)(ws + o_perm);
  int*  cnt  = (int*)(ws + o_cnt);
  int*  off  = (int*)(ws + o_off);
  int*  fill = (int*)(ws + o_fill);
  int*  nblk1 = (int*)(ws + o_nb1);
  int*  nblk2 = (int*)(ws + o_nb2);
  int4* tab1 = (int4*)(ws + o_tab1);
  int4* tab2 = (int4*)(ws + o_tab2);

  k_init<<<1, 64, 0, stream>>>(cnt, fill);
  k_gate<<<NTOK / 4, 256, 0, stream>>>(x, Wg, idx, cnt);
  k_cvt<<<(NTOK * HIDDEN / 4) / 256, 256, 0, stream>>>(x, xb, NTOK * HIDDEN / 4);
  k_wcvt<<<NMAT * 512, 256, 0, stream>>>(w1s, w2s, w3s, W1, W2, W3, Wb);
  k_table<<<1, 1, 0, stream>>>(cnt, off, tab1, nblk1, tab2, nblk2);
  k_scatter<<<NTOK / 256, 256, 0, stream>>>(idx, off, fill, perm);
  k_mlp1<<<dim3(MAXB1, INTER / 128), 512, 131072, stream>>>(xb, Wb, perm, tab1, nblk1, Hbuf);
  k_mlp2<<<dim3(MAXB2, HIDDEN / 256), 512, 98304, stream>>>(Hbuf, Wb, perm, tab2, nblk2, out, yexp);
  k_add<<<(NTOK * HIDDEN / 4) / 256, 256, 0, stream>>>(out, yexp, NTOK * HIDDEN / 4);
}

// Round 5
// 538.183 us; speedup vs baseline: 1.0437x; 1.0437x over previous
//
#include <hip/hip_runtime.h>
#include <stdint.h>

#define HIDDEN 1024
#define INTER  4096
#define NTOK   4096
#define HROWS  (2*NTOK)
#define MAXB1  40            // 256-row-granularity table (mlp1)
#define MAXB2  72            // 128-row-granularity table (mlp2)
#define NMAT   27            // 0..8: w1s,W1[0..7]; 9..17: w2s,W2; 18..26: w3s,W3

typedef unsigned short u16;
typedef unsigned int   u32;
typedef __bf16  bf16x8 __attribute__((ext_vector_type(8)));
typedef float   f32x4  __attribute__((ext_vector_type(4)));
typedef u32     u32x4  __attribute__((ext_vector_type(4)));

#define WAITVM(N) asm volatile("s_waitcnt vmcnt(" #N ")" ::: "memory")

__device__ __forceinline__ void hard_barrier() {
  asm volatile("" ::: "memory");
  __builtin_amdgcn_s_barrier();
  asm volatile("" ::: "memory");
}

__device__ __forceinline__ u16 f2bf(float f) {
  u32 u = __float_as_uint(f);
  u32 r = u + 0x7FFFu + ((u >> 16) & 1u);
  return (u16)(r >> 16);
}

__device__ __forceinline__ u32 cvt_pk_bf16(float lo, float hi) {
  u32 r;
  asm("v_cvt_pk_bf16_f32 %0, %1, %2" : "=v"(r) : "v"(lo), "v"(hi));
  return r;
}

__device__ __forceinline__ void glds16(const void* g, void* l) {
  __builtin_amdgcn_global_load_lds(
      (const __attribute__((address_space(1))) void*)g,
      (__attribute__((address_space(3))) void*)l, 16, 0, 0);
}

// ---------------- routing ----------------

__global__ void k_init(int* cnt, int* fill) {
  if (threadIdx.x < 8) { cnt[threadIdx.x] = 0; fill[threadIdx.x] = 0; }
}

__global__ __launch_bounds__(256) void k_gate(const float* __restrict__ x,
                                              const float* __restrict__ wg,
                                              int* __restrict__ idx,
                                              int* __restrict__ cnt) {
  int wave = threadIdx.x >> 6, lane = threadIdx.x & 63;
  int t = blockIdx.x * 4 + wave;
  if (t >= NTOK) return;
  float acc[8];
  #pragma unroll
  for (int e = 0; e < 8; ++e) acc[e] = 0.f;
  const float* xr = x + (size_t)t * HIDDEN;
  for (int c = lane; c < HIDDEN; c += 64) {
    float xv = xr[c];
    const float* wrow = wg + (size_t)c * 8;
    #pragma unroll
    for (int e = 0; e < 8; ++e) acc[e] += xv * wrow[e];
  }
  #pragma unroll
  for (int e = 0; e < 8; ++e)
    for (int s = 32; s; s >>= 1) acc[e] += __shfl_xor(acc[e], s);
  if (lane == 0) {
    int best = 0; float bv = acc[0];
    #pragma unroll
    for (int e = 1; e < 8; ++e) if (acc[e] > bv) { bv = acc[e]; best = e; }
    idx[t] = best;
    atomicAdd(&cnt[best], 1);
  }
}

__global__ void k_cvt(const float* __restrict__ x, u16* __restrict__ xb, int n4) {
  int i = blockIdx.x * blockDim.x + threadIdx.x;
  if (i >= n4) return;
  float4 v = ((const float4*)x)[i];
  ushort4 o;
  o.x = f2bf(v.x); o.y = f2bf(v.y); o.z = f2bf(v.z); o.w = f2bf(v.w);
  ((ushort4*)xb)[i] = o;
}

__global__ void k_table(const int* __restrict__ cnt, int* __restrict__ off,
                        int4* __restrict__ tab1, int* __restrict__ nblk1,
                        int4* __restrict__ tab2, int* __restrict__ nblk2) {
  if (threadIdx.x != 0 || blockIdx.x != 0) return;
  int o = 0;
  int offs[8];
  for (int e = 0; e < 8; ++e) { offs[e] = o; off[e] = o; o += cnt[e]; }
  int nb = 0;
  for (int m = 0; m < NTOK / 256; ++m)
    tab1[nb++] = make_int4(8, m * 256, 256, 0);
  for (int e = 0; e < 8; ++e)
    for (int j = 0; j * 256 < cnt[e]; ++j) {
      int rows = cnt[e] - j * 256; if (rows > 256) rows = 256;
      tab1[nb++] = make_int4(e, NTOK + offs[e] + j * 256, rows, offs[e] + j * 256);
    }
  *nblk1 = nb;
  nb = 0;
  for (int m = 0; m < NTOK / 128; ++m)
    tab2[nb++] = make_int4(8, m * 128, 128, 0);
  for (int e = 0; e < 8; ++e)
    for (int j = 0; j * 128 < cnt[e]; ++j) {
      int rows = cnt[e] - j * 128; if (rows > 128) rows = 128;
      tab2[nb++] = make_int4(e, NTOK + offs[e] + j * 128, rows, offs[e] + j * 128);
    }
  *nblk2 = nb;
}

__global__ void k_scatter(const int* __restrict__ idx, const int* __restrict__ off,
                          int* __restrict__ fill, int* __restrict__ perm) {
  int t = blockIdx.x * blockDim.x + threadIdx.x;
  if (t >= NTOK) return;
  int e = idx[t];
  int p = atomicAdd(&fill[e], 1);
  perm[off[e] + p] = t;
}

// ---------------- weight precvt: fp32 [K][N] -> bf16 pre-swizzled 8KB BK=32 panels ----------------
// Panel (matrix m, kt, pp): [128 n][32 k] bf16; u16 offset n*32 + s*8 + (k&7),
// slot s holds k-chunk (s ^ ((n>>1)&3)).  panelIdx = m*1024 + kt*Tp + pp
// (w1/w2: Tp=32; w3: Tp=8).  One block converts 2 adjacent panels (256 cols).

__global__ __launch_bounds__(256) void k_wcvt(
    const float* __restrict__ w1s, const float* __restrict__ w2s,
    const float* __restrict__ w3s, const float* __restrict__ W1,
    const float* __restrict__ W2,  const float* __restrict__ W3,
    u16* __restrict__ Wb)
{
  int bid = blockIdx.x;            // 0 .. 27*512-1
  int m = bid >> 9, pair = bid & 511;
  const float* src; int N, Tp, kt, pp2;
  if (m < 18) {
    N = INTER; Tp = 32;
    int mm = (m < 9) ? m : m - 9;
    const float* sp = (m < 9) ? w1s : w2s;
    const float* ep = (m < 9) ? W1 : W2;
    src = (mm == 0) ? sp : ep + (size_t)(mm - 1) * HIDDEN * INTER;
    kt = pair >> 4; pp2 = pair & 15;
  } else {
    N = HIDDEN; Tp = 8;
    int mm = m - 18;
    src = (mm == 0) ? w3s : W3 + (size_t)(mm - 1) * INTER * HIDDEN;
    kt = pair >> 2; pp2 = pair & 3;
  }

  __shared__ float tileF[32 * 256];
  int tid = threadIdx.x;
  const float* in0 = src + (size_t)(kt * 32) * N + pp2 * 256;
  #pragma unroll
  for (int i = 0; i < 8; ++i) {
    int f = tid + 256 * i;          // float4 index within 32x256 tile
    int k = f >> 6, c4 = f & 63;
    *(float4*)&tileF[k * 256 + c4 * 4] = *(const float4*)(in0 + (size_t)k * N + c4 * 4);
  }
  __syncthreads();

  int p2 = tid >> 7, n = tid & 127;
  u16* outp = Wb + ((size_t)m * 1024 + kt * Tp + pp2 * 2 + p2) * 4096 + n * 32;
  #pragma unroll
  for (int s = 0; s < 4; ++s) {
    int k8 = s ^ ((n >> 1) & 3);
    const float* col = &tileF[(k8 * 8) * 256 + p2 * 128 + n];
    u32x4 pk;
    pk.x = cvt_pk_bf16(col[0],    col[256]);
    pk.y = cvt_pk_bf16(col[512],  col[768]);
    pk.z = cvt_pk_bf16(col[1024], col[1280]);
    pk.w = cvt_pk_bf16(col[1536], col[1792]);
    *(u32x4*)(outp + s * 8) = pk;
  }
}

// ---------------- stage 1: H = gelu(Xg@W1) * (Xg@W2) ----------------
// 256x(128 dual) tile, 8 waves (2M x 4N), BK=32, 4-buffer counted-vmcnt pipeline,
// fine-grained 2-phases-per-tile schedule (16 MFMA per phase, T3+T4+T5).
// Per buffer (32KB): A [0,16384), B1 [16384,24576), B2 [24576,32768).

__global__ __launch_bounds__(512, 2) void k_mlp1(
    const u16* __restrict__ xb, const u16* __restrict__ Wb,
    const int* __restrict__ perm, const int4* __restrict__ tab,
    const int* __restrict__ nblk, u16* __restrict__ Hbuf)
{
  int bx = blockIdx.x;
  if (bx >= *nblk) return;
  int4 te = tab[bx];
  int g = te.x, hrow0 = te.y, rows = te.z, pb = te.w;
  int m1 = (g == 8) ? 0 : 1 + g;
  int pp = blockIdx.y;
  int nbase = pp * 128;

  extern __shared__ __align__(16) char smem[];
  int tid = threadIdx.x;
  int w = tid >> 6, lane = tid & 63;
  int q = lane >> 4, rl = lane & 15;
  int mw = w >> 2, nw = w & 3;

  int tokj[2];
  #pragma unroll
  for (int j = 0; j < 2; ++j) {
    int r = w * 32 + j * 16 + (lane >> 2);
    int rc = (r < rows) ? r : (rows - 1);
    tokj[j] = (g == 8) ? (hrow0 + rc) : perm[pb + rc];
  }
  int gch = ((lane & 3) ^ ((lane >> 3) & 3)) * 16;   // source chunk byte offset

  const char* pB1 = (const char*)Wb + ((size_t)m1 * 1024 + pp) * 8192;
  const char* pB2 = (const char*)Wb + ((size_t)(m1 + 9) * 1024 + pp) * 8192;

  f32x4 acc1[8][2], acc2[8][2];
  f32x4 z = {0.f, 0.f, 0.f, 0.f};
  #pragma unroll
  for (int mi = 0; mi < 8; ++mi)
    #pragma unroll
    for (int ni = 0; ni < 2; ++ni) { acc1[mi][ni] = z; acc2[mi][ni] = z; }

  // per-tile load batch order: [A, A, B1, B2] (4 glds/wave/tile)
  auto STAGE_A = [&](int t) {
    char* L = smem + (t & 3) * 32768;
    int k0 = t * 32;
    #pragma unroll
    for (int j = 0; j < 2; ++j) {
      const char* src = (const char*)xb + ((size_t)tokj[j] * HIDDEN + k0) * 2 + gch;
      glds16(src, L + w * 2048 + j * 1024);
    }
  };
  auto STAGE_B = [&](int t) {
    char* L = smem + (t & 3) * 32768;
    glds16(pB1 + (size_t)t * 262144 + (tid << 4), L + 16384 + w * 1024);
    glds16(pB2 + (size_t)t * 262144 + (tid << 4), L + 24576 + w * 1024);
  };

  int co = (q ^ ((rl >> 1) & 3)) * 8;

  const int NT = HIDDEN / 32;
  STAGE_A(0); STAGE_B(0);
  STAGE_A(1); STAGE_B(1);
  STAGE_A(2); STAGE_B(2);
  WAITVM(8);            // 12 out, drain oldest 4 = tile 0
  hard_barrier();

  for (int t = 0; t < NT; ++t) {
    const u16* LA  = (const u16*)(smem + (t & 3) * 32768);
    const u16* LB1 = LA + 8192;
    const u16* LB2 = LA + 12288;
    bf16x8 af[8], b1[2], b2[2];

    // ---- phase 1: frag-reads (8 ds) + A-stage(t+3) + 16 MFMA ----
    #pragma unroll
    for (int mi = 0; mi < 4; ++mi)
      af[mi] = *(const bf16x8*)&LA[(mw * 128 + mi * 16 + rl) * 32 + co];
    #pragma unroll
    for (int ni = 0; ni < 2; ++ni) {
      int n = nw * 32 + ni * 16 + rl;
      b1[ni] = *(const bf16x8*)&LB1[n * 32 + co];
      b2[ni] = *(const bf16x8*)&LB2[n * 32 + co];
    }
    if (t + 3 < NT) STAGE_A(t + 3);
    __builtin_amdgcn_s_setprio(1);
    #pragma unroll
    for (int mi = 0; mi < 4; ++mi)
      #pragma unroll
      for (int ni = 0; ni < 2; ++ni) {
        acc1[mi][ni] = __builtin_amdgcn_mfma_f32_16x16x32_bf16(af[mi], b1[ni], acc1[mi][ni], 0, 0, 0);
        acc2[mi][ni] = __builtin_amdgcn_mfma_f32_16x16x32_bf16(af[mi], b2[ni], acc2[mi][ni], 0, 0, 0);
      }
    __builtin_amdgcn_s_setprio(0);
    hard_barrier();

    // ---- phase 2: frag-reads (4 ds) + B-stage(t+3) + 16 MFMA + counted wait ----
    #pragma unroll
    for (int mi = 4; mi < 8; ++mi)
      af[mi] = *(const bf16x8*)&LA[(mw * 128 + mi * 16 + rl) * 32 + co];
    if (t + 3 < NT) STAGE_B(t + 3);
    __builtin_amdgcn_s_setprio(1);
    #pragma unroll
    for (int mi = 4; mi < 8; ++mi)
      #pragma unroll
      for (int ni = 0; ni < 2; ++ni) {
        acc1[mi][ni] = __builtin_amdgcn_mfma_f32_16x16x32_bf16(af[mi], b1[ni], acc1[mi][ni], 0, 0, 0);
        acc2[mi][ni] = __builtin_amdgcn_mfma_f32_16x16x32_bf16(af[mi], b2[ni], acc2[mi][ni], 0, 0, 0);
      }
    __builtin_amdgcn_s_setprio(0);
    {
      int rem = NT - 1 - t;          // ensure tile t+1 landed before barrier
      if (rem >= 3)      WAITVM(8);  // out: t+1(4)+t+2(4)+t+3(4) -> allow 8
      else if (rem == 2) WAITVM(4);  // out: t+1(4)+t+2(4)        -> allow 4
      else if (rem == 1) WAITVM(0);  // out: t+1(4)               -> allow 0
    }
    hard_barrier();
  }

  #pragma unroll
  for (int mi = 0; mi < 8; ++mi) {
    #pragma unroll
    for (int j = 0; j < 4; ++j) {
      int r = mw * 128 + mi * 16 + q * 4 + j;
      if (r < rows) {
        size_t hb = (size_t)(hrow0 + r) * INTER + nbase + nw * 32;
        #pragma unroll
        for (int ni = 0; ni < 2; ++ni) {
          float h1 = acc1[mi][ni][j];
          float h2 = acc2[mi][ni][j];
          float ge = 0.5f * h1 * (1.0f + erff(h1 * 0.7071067811865476f));
          Hbuf[hb + ni * 16 + rl] = f2bf(ge * h2);
        }
      }
    }
  }
}

// ---------------- stage 2: Y = H @ W3 ----------------
// 128x256 tile, 8 waves (2M x 4N), BK=32, 4-buffer counted-vmcnt pipeline,
// 1 phase per tile (16 MFMA per phase).
// Per buffer (24KB): A [0,8192), B [8192,24576) (two 8KB panels concat).

__global__ __launch_bounds__(512, 2) void k_mlp2(
    const u16* __restrict__ Hbuf, const u16* __restrict__ Wb,
    const int* __restrict__ perm, const int4* __restrict__ tab,
    const int* __restrict__ nblk, float* __restrict__ out,
    float* __restrict__ yexp)
{
  int bx = blockIdx.x;
  if (bx >= *nblk) return;
  int4 te = tab[bx];
  int g = te.x, hrow0 = te.y, rows = te.z, pb = te.w;
  int m3 = (g == 8) ? 18 : 19 + g;
  int pp2 = blockIdx.y;

  extern __shared__ __align__(16) char smem[];
  int tid = threadIdx.x;
  int w = tid >> 6, lane = tid & 63;
  int q = lane >> 4, rl = lane & 15;
  int mw = w >> 2, nw = w & 3;

  int rr = w * 16 + (lane >> 2);
  int rc = (rr < rows) ? rr : (rows - 1);
  int hr = hrow0 + rc;
  int gch = ((lane & 3) ^ ((lane >> 3) & 3)) * 16;

  const char* pB = (const char*)Wb + ((size_t)m3 * 1024 + pp2 * 2) * 8192;

  f32x4 acc[4][4];
  f32x4 z = {0.f, 0.f, 0.f, 0.f};
  #pragma unroll
  for (int mi = 0; mi < 4; ++mi)
    #pragma unroll
    for (int ni = 0; ni < 4; ++ni) acc[mi][ni] = z;

  // 3 glds/wave/tile: [A, B0, B1]
  auto STAGE = [&](int t) {
    char* L = smem + (t & 3) * 24576;
    int k0 = t * 32;
    const char* src = (const char*)Hbuf + ((size_t)hr * INTER + k0) * 2 + gch;
    glds16(src, L + w * 1024);
    #pragma unroll
    for (int j = 0; j < 2; ++j)
      glds16(pB + (size_t)t * 65536 + j * 8192 + (tid << 4), L + 8192 + j * 8192 + w * 1024);
  };

  int co = (q ^ ((rl >> 1) & 3)) * 8;

  const int NT = INTER / 32;
  STAGE(0); STAGE(1); STAGE(2);
  WAITVM(6);            // 9 out, drain oldest 3 = tile 0
  hard_barrier();

  for (int t = 0; t < NT; ++t) {
    const u16* LA = (const u16*)(smem + (t & 3) * 24576);
    const u16* LB = LA + 4096;
    bf16x8 af[4], bf[4];
    #pragma unroll
    for (int mi = 0; mi < 4; ++mi)
      af[mi] = *(const bf16x8*)&LA[(mw * 64 + mi * 16 + rl) * 32 + co];
    #pragma unroll
    for (int ni = 0; ni < 4; ++ni) {
      int n = nw * 64 + ni * 16 + rl;
      bf[ni] = *(const bf16x8*)&LB[n * 32 + co];
    }
    if (t + 3 < NT) STAGE(t + 3);
    __builtin_amdgcn_s_setprio(1);
    #pragma unroll
    for (int mi = 0; mi < 4; ++mi)
      #pragma unroll
      for (int ni = 0; ni < 4; ++ni)
        acc[mi][ni] = __builtin_amdgcn_mfma_f32_16x16x32_bf16(af[mi], bf[ni], acc[mi][ni], 0, 0, 0);
    __builtin_amdgcn_s_setprio(0);
    {
      int rem = NT - 1 - t;          // ensure tile t+1 landed before barrier
      if (rem >= 3)      WAITVM(6);  // out: t+1(3)+t+2(3)+t+3(3) -> allow 6
      else if (rem == 2) WAITVM(3);
      else if (rem == 1) WAITVM(0);
    }
    hard_barrier();
  }

  float* dstb = (g == 8) ? out : yexp;
  #pragma unroll
  for (int mi = 0; mi < 4; ++mi) {
    #pragma unroll
    for (int j = 0; j < 4; ++j) {
      int r = mw * 64 + mi * 16 + q * 4 + j;
      if (r < rows) {
        int tok = (g == 8) ? (hrow0 + r) : perm[pb + r];
        size_t ob = (size_t)tok * HIDDEN + pp2 * 256 + nw * 64;
        #pragma unroll
        for (int ni = 0; ni < 4; ++ni)
          dstb[ob + ni * 16 + rl] = acc[mi][ni][j];
      }
    }
  }
}

__global__ void k_add(float* __restrict__ out, const float* __restrict__ yexp, int n4) {
  int i = blockIdx.x * blockDim.x + threadIdx.x;
  if (i >= n4) return;
  float4 a = ((const float4*)out)[i];
  float4 b = ((const float4*)yexp)[i];
  a.x += b.x; a.y += b.y; a.z += b.z; a.w += b.w;
  ((float4*)out)[i] = a;
}

// ---------------- launcher ----------------

extern "C" void kernel_launch(void* const* d_in, const int* in_sizes, int n_in,
                              void* d_out, int out_size, void* d_ws, size_t ws_size,
                              hipStream_t stream) {
  const float* x   = (const float*)d_in[0];
  const float* w1s = (const float*)d_in[1];
  const float* w2s = (const float*)d_in[2];
  const float* w3s = (const float*)d_in[3];
  const float* W1  = (const float*)d_in[4];
  const float* W2  = (const float*)d_in[5];
  const float* W3  = (const float*)d_in[6];
  const float* Wg  = (const float*)d_in[7];
  float* out = (float*)d_out;

  char* ws = (char*)d_ws;
  size_t o_xb   = 0;
  size_t o_H    = o_xb   + (size_t)NTOK * HIDDEN * 2;           // 8 MB
  size_t o_yexp = o_H    + (size_t)HROWS * INTER * 2;           // +64 MB
  size_t o_Wb   = o_yexp + (size_t)NTOK * HIDDEN * 4;           // +16 MB
  size_t o_idx  = o_Wb   + (size_t)NMAT * 1024 * 8192;          // +216 MB
  size_t o_perm = o_idx  + (size_t)NTOK * 4;
  size_t o_cnt  = o_perm + (size_t)NTOK * 4;
  size_t o_off  = o_cnt  + 32;
  size_t o_fill = o_off  + 32;
  size_t o_nb1  = o_fill + 32;
  size_t o_nb2  = o_nb1  + 32;
  size_t o_tab1 = o_nb2  + 32;
  size_t o_tab2 = o_tab1 + (size_t)MAXB1 * 16;
  size_t need   = o_tab2 + (size_t)MAXB2 * 16;
  if (ws_size < need) return;  // insufficient scratch

  u16*  xb   = (u16*)(ws + o_xb);
  u16*  Hbuf = (u16*)(ws + o_H);
  float* yexp = (float*)(ws + o_yexp);
  u16*  Wb   = (u16*)(ws + o_Wb);
  int*  idx  = (int*)(ws + o_idx);
  int*  perm = (int*)(ws + o_perm);
  int*  cnt  = (int*)(ws + o_cnt);
  int*  off  = (int*)(ws + o_off);
  int*  fill = (int*)(ws + o_fill);
  int*  nblk1 = (int*)(ws + o_nb1);
  int*  nblk2 = (int*)(ws + o_nb2);
  int4* tab1 = (int4*)(ws + o_tab1);
  int4* tab2 = (int4*)(ws + o_tab2);

  k_init<<<1, 64, 0, stream>>>(cnt, fill);
  k_gate<<<NTOK / 4, 256, 0, stream>>>(x, Wg, idx, cnt);
  k_cvt<<<(NTOK * HIDDEN / 4) / 256, 256, 0, stream>>>(x, xb, NTOK * HIDDEN / 4);
  k_wcvt<<<NMAT * 512, 256, 0, stream>>>(w1s, w2s, w3s, W1, W2, W3, Wb);
  k_table<<<1, 1, 0, stream>>>(cnt, off, tab1, nblk1, tab2, nblk2);
  k_scatter<<<NTOK / 256, 256, 0, stream>>>(idx, off, fill, perm);
  k_mlp1<<<dim3(MAXB1, INTER / 128), 512, 131072, stream>>>(xb, Wb, perm, tab1, nblk1, Hbuf);
  k_mlp2<<<dim3(MAXB2, HIDDEN / 256), 512, 98304, stream>>>(Hbuf, Wb, perm, tab2, nblk2, out, yexp);
  k_add<<<(NTOK * HIDDEN / 4) / 256, 256, 0, stream>>>(out, yexp, NTOK * HIDDEN / 4);
}

// Round 6
// 524.010 us; speedup vs baseline: 1.0720x; 1.0270x over previous
//
#include <hip/hip_runtime.h>
#include <stdint.h>

#define HIDDEN 1024
#define INTER  4096
#define NTOK   4096
#define HROWS  (2*NTOK)
#define MAXB1  40            // 256-row-granularity table (mlp1)
#define MAXB2  72            // 128-row-granularity table (mlp2)
#define NMAT   27            // 0..8: w1s,W1[0..7]; 9..17: w2s,W2; 18..26: w3s,W3

typedef unsigned short u16;
typedef unsigned int   u32;
typedef __bf16  bf16x8 __attribute__((ext_vector_type(8)));
typedef float   f32x4  __attribute__((ext_vector_type(4)));
typedef u32     u32x4  __attribute__((ext_vector_type(4)));

#define WAITVM(N) asm volatile("s_waitcnt vmcnt(" #N ")" ::: "memory")

__device__ __forceinline__ void hard_barrier() {
  asm volatile("" ::: "memory");
  __builtin_amdgcn_s_barrier();
  asm volatile("" ::: "memory");
}

__device__ __forceinline__ u16 f2bf(float f) {
  u32 u = __float_as_uint(f);
  u32 r = u + 0x7FFFu + ((u >> 16) & 1u);
  return (u16)(r >> 16);
}

__device__ __forceinline__ u32 cvt_pk_bf16(float lo, float hi) {
  u32 r;
  asm("v_cvt_pk_bf16_f32 %0, %1, %2" : "=v"(r) : "v"(lo), "v"(hi));
  return r;
}

__device__ __forceinline__ void glds16(const void* g, void* l) {
  __builtin_amdgcn_global_load_lds(
      (const __attribute__((address_space(1))) void*)g,
      (__attribute__((address_space(3))) void*)l, 16, 0, 0);
}

// ---------------- routing ----------------

__global__ void k_init(int* cnt, int* fill) {
  if (threadIdx.x < 8) { cnt[threadIdx.x] = 0; fill[threadIdx.x] = 0; }
}

__global__ __launch_bounds__(256) void k_gate(const float* __restrict__ x,
                                              const float* __restrict__ wg,
                                              int* __restrict__ idx,
                                              int* __restrict__ cnt) {
  int wave = threadIdx.x >> 6, lane = threadIdx.x & 63;
  int t = blockIdx.x * 4 + wave;
  if (t >= NTOK) return;
  float acc[8];
  #pragma unroll
  for (int e = 0; e < 8; ++e) acc[e] = 0.f;
  const float* xr = x + (size_t)t * HIDDEN;
  for (int c = lane; c < HIDDEN; c += 64) {
    float xv = xr[c];
    const float* wrow = wg + (size_t)c * 8;
    #pragma unroll
    for (int e = 0; e < 8; ++e) acc[e] += xv * wrow[e];
  }
  #pragma unroll
  for (int e = 0; e < 8; ++e)
    for (int s = 32; s; s >>= 1) acc[e] += __shfl_xor(acc[e], s);
  if (lane == 0) {
    int best = 0; float bv = acc[0];
    #pragma unroll
    for (int e = 1; e < 8; ++e) if (acc[e] > bv) { bv = acc[e]; best = e; }
    idx[t] = best;
    atomicAdd(&cnt[best], 1);
  }
}

__global__ void k_cvt(const float* __restrict__ x, u16* __restrict__ xb, int n4) {
  int i = blockIdx.x * blockDim.x + threadIdx.x;
  if (i >= n4) return;
  float4 v = ((const float4*)x)[i];
  ushort4 o;
  o.x = f2bf(v.x); o.y = f2bf(v.y); o.z = f2bf(v.z); o.w = f2bf(v.w);
  ((ushort4*)xb)[i] = o;
}

__global__ void k_table(const int* __restrict__ cnt, int* __restrict__ off,
                        int4* __restrict__ tab1, int* __restrict__ nblk1,
                        int4* __restrict__ tab2, int* __restrict__ nblk2) {
  if (threadIdx.x != 0 || blockIdx.x != 0) return;
  int o = 0;
  int offs[8];
  for (int e = 0; e < 8; ++e) { offs[e] = o; off[e] = o; o += cnt[e]; }
  int nb = 0;
  for (int m = 0; m < NTOK / 256; ++m)
    tab1[nb++] = make_int4(8, m * 256, 256, 0);
  for (int e = 0; e < 8; ++e)
    for (int j = 0; j * 256 < cnt[e]; ++j) {
      int rows = cnt[e] - j * 256; if (rows > 256) rows = 256;
      tab1[nb++] = make_int4(e, NTOK + offs[e] + j * 256, rows, offs[e] + j * 256);
    }
  *nblk1 = nb;
  nb = 0;
  for (int m = 0; m < NTOK / 128; ++m)
    tab2[nb++] = make_int4(8, m * 128, 128, 0);
  for (int e = 0; e < 8; ++e)
    for (int j = 0; j * 128 < cnt[e]; ++j) {
      int rows = cnt[e] - j * 128; if (rows > 128) rows = 128;
      tab2[nb++] = make_int4(e, NTOK + offs[e] + j * 128, rows, offs[e] + j * 128);
    }
  *nblk2 = nb;
}

__global__ void k_scatter(const int* __restrict__ idx, const int* __restrict__ off,
                          int* __restrict__ fill, int* __restrict__ perm) {
  int t = blockIdx.x * blockDim.x + threadIdx.x;
  if (t >= NTOK) return;
  int e = idx[t];
  int p = atomicAdd(&fill[e], 1);
  perm[off[e] + p] = t;
}

// ---------------- weight precvt: fp32 [K][N] -> bf16 pre-swizzled 8KB BK=32 panels ----------------
// Panel (matrix m, col-panel cp, kt): [128 n][32 k] bf16; u16 offset n*32 + s*8 + (k&7),
// slot s holds k-chunk (s ^ ((n>>1)&3)).
// K-CONTIGUOUS panel order: pidx = m*1024 + cp*NKT + kt  (w1/w2: NKT=32; w3: NKT=128).

__global__ __launch_bounds__(256) void k_wcvt(
    const float* __restrict__ w1s, const float* __restrict__ w2s,
    const float* __restrict__ w3s, const float* __restrict__ W1,
    const float* __restrict__ W2,  const float* __restrict__ W3,
    u16* __restrict__ Wb)
{
  int bid = blockIdx.x;            // 0 .. 27*512-1
  int m = bid >> 9, pair = bid & 511;
  const float* src; int N, nkt, kt, pp2;
  if (m < 18) {
    N = INTER; nkt = 32;
    int mm = (m < 9) ? m : m - 9;
    const float* sp = (m < 9) ? w1s : w2s;
    const float* ep = (m < 9) ? W1 : W2;
    src = (mm == 0) ? sp : ep + (size_t)(mm - 1) * HIDDEN * INTER;
    kt = pair >> 4; pp2 = pair & 15;
  } else {
    N = HIDDEN; nkt = 128;
    int mm = m - 18;
    src = (mm == 0) ? w3s : W3 + (size_t)(mm - 1) * INTER * HIDDEN;
    kt = pair >> 2; pp2 = pair & 3;
  }

  __shared__ float tileF[32 * 256];
  int tid = threadIdx.x;
  const float* in0 = src + (size_t)(kt * 32) * N + pp2 * 256;
  #pragma unroll
  for (int i = 0; i < 8; ++i) {
    int f = tid + 256 * i;          // float4 index within 32x256 tile
    int k = f >> 6, c4 = f & 63;
    *(float4*)&tileF[k * 256 + c4 * 4] = *(const float4*)(in0 + (size_t)k * N + c4 * 4);
  }
  __syncthreads();

  int p2 = tid >> 7, n = tid & 127;
  int pidx = m * 1024 + (pp2 * 2 + p2) * nkt + kt;
  u16* outp = Wb + (size_t)pidx * 4096 + n * 32;
  #pragma unroll
  for (int s = 0; s < 4; ++s) {
    int k8 = s ^ ((n >> 1) & 3);
    const float* col = &tileF[(k8 * 8) * 256 + p2 * 128 + n];
    u32x4 pk;
    pk.x = cvt_pk_bf16(col[0],    col[256]);
    pk.y = cvt_pk_bf16(col[512],  col[768]);
    pk.z = cvt_pk_bf16(col[1024], col[1280]);
    pk.w = cvt_pk_bf16(col[1536], col[1792]);
    *(u32x4*)(outp + s * 8) = pk;
  }
}

// ---------------- stage 1: H = gelu(Xg@W1) * (Xg@W2) ----------------
// 256x(128 dual) tile, 8 waves (2M x 4N), BK=32, 4-buffer counted-vmcnt pipeline.
// Unrolled x4 with compile-time buffer indices; all LDS/global addresses hoisted.
// Per buffer (32KB): A [0,16384), B1 [16384,24576), B2 [24576,32768).

#define MLP1_TILE(B, STG, WN)                                                        \
  do {                                                                               \
    const u16* LA = pAr  + (B) * 16384;                                              \
    const u16* L1 = pBr1 + (B) * 16384;                                              \
    const u16* L2 = pBr2 + (B) * 16384;                                              \
    bf16x8 af[8], f1[2], f2[2];                                                      \
    _Pragma("unroll")                                                                \
    for (int mi = 0; mi < 4; ++mi) af[mi] = *(const bf16x8*)(LA + mi * 512);         \
    _Pragma("unroll")                                                                \
    for (int ni = 0; ni < 2; ++ni) {                                                 \
      f1[ni] = *(const bf16x8*)(L1 + ni * 512);                                      \
      f2[ni] = *(const bf16x8*)(L2 + ni * 512);                                      \
    }                                                                                \
    if (STG) {                                                                       \
      char* Ld = smem + (((B) + 3) & 3) * 32768;                                     \
      glds16(srcA0, Ld + w * 2048);                                                  \
      glds16(srcA1, Ld + w * 2048 + 1024);                                           \
      srcA0 += 64; srcA1 += 64;                                                      \
    }                                                                                \
    __builtin_amdgcn_s_setprio(1);                                                   \
    _Pragma("unroll")                                                                \
    for (int mi = 0; mi < 4; ++mi) {                                                 \
      acc1[mi][0] = __builtin_amdgcn_mfma_f32_16x16x32_bf16(af[mi], f1[0], acc1[mi][0], 0, 0, 0); \
      acc1[mi][1] = __builtin_amdgcn_mfma_f32_16x16x32_bf16(af[mi], f1[1], acc1[mi][1], 0, 0, 0); \
      acc2[mi][0] = __builtin_amdgcn_mfma_f32_16x16x32_bf16(af[mi], f2[0], acc2[mi][0], 0, 0, 0); \
      acc2[mi][1] = __builtin_amdgcn_mfma_f32_16x16x32_bf16(af[mi], f2[1], acc2[mi][1], 0, 0, 0); \
    }                                                                                \
    __builtin_amdgcn_s_setprio(0);                                                   \
    hard_barrier();                                                                  \
    _Pragma("unroll")                                                                \
    for (int mi = 4; mi < 8; ++mi) af[mi] = *(const bf16x8*)(LA + mi * 512);         \
    if (STG) {                                                                       \
      char* Ld = smem + (((B) + 3) & 3) * 32768;                                     \
      glds16(srcB1, Ld + 16384 + w * 1024);                                          \
      glds16(srcB2, Ld + 24576 + w * 1024);                                          \
      srcB1 += 8192; srcB2 += 8192;                                                  \
    }                                                                                \
    __builtin_amdgcn_s_setprio(1);                                                   \
    _Pragma("unroll")                                                                \
    for (int mi = 4; mi < 8; ++mi) {                                                 \
      acc1[mi][0] = __builtin_amdgcn_mfma_f32_16x16x32_bf16(af[mi], f1[0], acc1[mi][0], 0, 0, 0); \
      acc1[mi][1] = __builtin_amdgcn_mfma_f32_16x16x32_bf16(af[mi], f1[1], acc1[mi][1], 0, 0, 0); \
      acc2[mi][0] = __builtin_amdgcn_mfma_f32_16x16x32_bf16(af[mi], f2[0], acc2[mi][0], 0, 0, 0); \
      acc2[mi][1] = __builtin_amdgcn_mfma_f32_16x16x32_bf16(af[mi], f2[1], acc2[mi][1], 0, 0, 0); \
    }                                                                                \
    __builtin_amdgcn_s_setprio(0);                                                   \
    WN;                                                                              \
    hard_barrier();                                                                  \
  } while (0)

__global__ __launch_bounds__(512, 2) void k_mlp1(
    const u16* __restrict__ xb, const u16* __restrict__ Wb,
    const int* __restrict__ perm, const int4* __restrict__ tab,
    const int* __restrict__ nblk, u16* __restrict__ Hbuf)
{
  int bx = blockIdx.x;
  if (bx >= *nblk) return;
  int4 te = tab[bx];
  int g = te.x, hrow0 = te.y, rows = te.z, pb = te.w;
  int m1 = (g == 8) ? 0 : 1 + g;
  int pp = blockIdx.y;
  int nbase = pp * 128;

  extern __shared__ __align__(16) char smem[];
  int tid = threadIdx.x;
  int w = tid >> 6, lane = tid & 63;
  int q = lane >> 4, rl = lane & 15;
  int mw = w >> 2, nw = w & 3;

  int tokj[2];
  #pragma unroll
  for (int j = 0; j < 2; ++j) {
    int r = w * 32 + j * 16 + (lane >> 2);
    int rc = (r < rows) ? r : (rows - 1);
    tokj[j] = (g == 8) ? (hrow0 + rc) : perm[pb + rc];
  }
  int gch = ((lane & 3) ^ ((lane >> 3) & 3)) * 16;   // source chunk byte offset

  // running staging pointers (advance by constants per tile)
  const char* srcA0 = (const char*)xb + (size_t)tokj[0] * 2048 + gch;
  const char* srcA1 = (const char*)xb + (size_t)tokj[1] * 2048 + gch;
  const char* srcB1 = (const char*)Wb + ((size_t)m1 * 1024 + pp * 32) * 8192 + (tid << 4);
  const char* srcB2 = (const char*)Wb + ((size_t)(m1 + 9) * 1024 + pp * 32) * 8192 + (tid << 4);

  // hoisted LDS frag pointers
  int co = (q ^ ((rl >> 1) & 3)) * 8;
  const u16* pAr  = (const u16*)smem + (mw * 128 + rl) * 32 + co;
  const u16* pBr1 = (const u16*)smem + 8192  + (nw * 32 + rl) * 32 + co;
  const u16* pBr2 = (const u16*)smem + 12288 + (nw * 32 + rl) * 32 + co;

  f32x4 acc1[8][2], acc2[8][2];
  f32x4 z = {0.f, 0.f, 0.f, 0.f};
  #pragma unroll
  for (int mi = 0; mi < 8; ++mi)
    #pragma unroll
    for (int ni = 0; ni < 2; ++ni) { acc1[mi][ni] = z; acc2[mi][ni] = z; }

  // prologue: stage tiles 0,1,2 (4 loads each: A,A,B1,B2)
  #pragma unroll
  for (int p = 0; p < 3; ++p) {
    char* Ld = smem + p * 32768;
    glds16(srcA0, Ld + w * 2048);
    glds16(srcA1, Ld + w * 2048 + 1024);
    srcA0 += 64; srcA1 += 64;
    glds16(srcB1, Ld + 16384 + w * 1024);
    glds16(srcB2, Ld + 24576 + w * 1024);
    srcB1 += 8192; srcB2 += 8192;
  }
  WAITVM(8);           // 12 out, drain tile 0's 4
  hard_barrier();

  // NT = 32 tiles; main: tiles 0..27 (always stage, WAITVM(8)); tail: 28..31
  for (int t0 = 0; t0 < 28; t0 += 4) {
    MLP1_TILE(0, 1, WAITVM(8));
    MLP1_TILE(1, 1, WAITVM(8));
    MLP1_TILE(2, 1, WAITVM(8));
    MLP1_TILE(3, 1, WAITVM(8));
  }
  MLP1_TILE(0, 1, WAITVM(8));
  MLP1_TILE(1, 0, WAITVM(4));
  MLP1_TILE(2, 0, WAITVM(0));
  MLP1_TILE(3, 0, (void)0);

  #pragma unroll
  for (int mi = 0; mi < 8; ++mi) {
    #pragma unroll
    for (int j = 0; j < 4; ++j) {
      int r = mw * 128 + mi * 16 + q * 4 + j;
      if (r < rows) {
        size_t hb = (size_t)(hrow0 + r) * INTER + nbase + nw * 32;
        #pragma unroll
        for (int ni = 0; ni < 2; ++ni) {
          float h1 = acc1[mi][ni][j];
          float h2 = acc2[mi][ni][j];
          float ge = 0.5f * h1 * (1.0f + erff(h1 * 0.7071067811865476f));
          Hbuf[hb + ni * 16 + rl] = f2bf(ge * h2);
        }
      }
    }
  }
}

// ---------------- stage 2: Y = H @ W3 ----------------
// 128x256 tile, 8 waves (2M x 4N), BK=32, 4-buffer counted-vmcnt pipeline, unrolled x4.
// Per buffer (24KB): A [0,8192), B [8192,24576) (two 8KB panels concat).

#define MLP2_TILE(B, STG, WN)                                                        \
  do {                                                                               \
    const u16* LA = pAr + (B) * 12288;                                               \
    const u16* LB = pBr + (B) * 12288;                                               \
    bf16x8 af[4], bf[4];                                                             \
    _Pragma("unroll")                                                                \
    for (int mi = 0; mi < 4; ++mi) af[mi] = *(const bf16x8*)(LA + mi * 512);         \
    _Pragma("unroll")                                                                \
    for (int ni = 0; ni < 4; ++ni) bf[ni] = *(const bf16x8*)(LB + ni * 512);         \
    if (STG) {                                                                       \
      char* Ld = smem + (((B) + 3) & 3) * 24576;                                     \
      glds16(srcA0, Ld + w * 1024);              srcA0 += 64;                        \
      glds16(srcB0, Ld + 8192 + w * 1024);       srcB0 += 8192;                      \
      glds16(srcB1, Ld + 16384 + w * 1024);      srcB1 += 8192;                      \
    }                                                                                \
    __builtin_amdgcn_s_setprio(1);                                                   \
    _Pragma("unroll")                                                                \
    for (int mi = 0; mi < 4; ++mi)                                                   \
      _Pragma("unroll")                                                              \
      for (int ni = 0; ni < 4; ++ni)                                                 \
        acc[mi][ni] = __builtin_amdgcn_mfma_f32_16x16x32_bf16(af[mi], bf[ni], acc[mi][ni], 0, 0, 0); \
    __builtin_amdgcn_s_setprio(0);                                                   \
    WN;                                                                              \
    hard_barrier();                                                                  \
  } while (0)

__global__ __launch_bounds__(512, 2) void k_mlp2(
    const u16* __restrict__ Hbuf, const u16* __restrict__ Wb,
    const int* __restrict__ perm, const int4* __restrict__ tab,
    const int* __restrict__ nblk, float* __restrict__ out,
    float* __restrict__ yexp)
{
  int bx = blockIdx.x;
  if (bx >= *nblk) return;
  int4 te = tab[bx];
  int g = te.x, hrow0 = te.y, rows = te.z, pb = te.w;
  int m3 = (g == 8) ? 18 : 19 + g;
  int pp2 = blockIdx.y;

  extern __shared__ __align__(16) char smem[];
  int tid = threadIdx.x;
  int w = tid >> 6, lane = tid & 63;
  int q = lane >> 4, rl = lane & 15;
  int mw = w >> 2, nw = w & 3;

  int rr = w * 16 + (lane >> 2);
  int rc = (rr < rows) ? rr : (rows - 1);
  int hr = hrow0 + rc;
  int gch = ((lane & 3) ^ ((lane >> 3) & 3)) * 16;

  const char* srcA0 = (const char*)Hbuf + (size_t)hr * (INTER * 2) + gch;
  const char* srcB0 = (const char*)Wb + ((size_t)m3 * 1024 + (pp2 * 2) * 128) * 8192 + (tid << 4);
  const char* srcB1 = (const char*)Wb + ((size_t)m3 * 1024 + (pp2 * 2 + 1) * 128) * 8192 + (tid << 4);

  int co = (q ^ ((rl >> 1) & 3)) * 8;
  const u16* pAr = (const u16*)smem + (mw * 64 + rl) * 32 + co;
  const u16* pBr = (const u16*)smem + 4096 + (nw * 64 + rl) * 32 + co;

  f32x4 acc[4][4];
  f32x4 z = {0.f, 0.f, 0.f, 0.f};
  #pragma unroll
  for (int mi = 0; mi < 4; ++mi)
    #pragma unroll
    for (int ni = 0; ni < 4; ++ni) acc[mi][ni] = z;

  // prologue: stage tiles 0,1,2 (3 loads each: A,B0,B1)
  #pragma unroll
  for (int p = 0; p < 3; ++p) {
    char* Ld = smem + p * 24576;
    glds16(srcA0, Ld + w * 1024);          srcA0 += 64;
    glds16(srcB0, Ld + 8192 + w * 1024);   srcB0 += 8192;
    glds16(srcB1, Ld + 16384 + w * 1024);  srcB1 += 8192;
  }
  WAITVM(6);           // 9 out, drain tile 0's 3
  hard_barrier();

  // NT = 128; main: tiles 0..123 (stage, WAITVM(6)); tail: 124..127
  for (int t0 = 0; t0 < 124; t0 += 4) {
    MLP2_TILE(0, 1, WAITVM(6));
    MLP2_TILE(1, 1, WAITVM(6));
    MLP2_TILE(2, 1, WAITVM(6));
    MLP2_TILE(3, 1, WAITVM(6));
  }
  MLP2_TILE(0, 1, WAITVM(6));
  MLP2_TILE(1, 0, WAITVM(3));
  MLP2_TILE(2, 0, WAITVM(0));
  MLP2_TILE(3, 0, (void)0);

  float* dstb = (g == 8) ? out : yexp;
  #pragma unroll
  for (int mi = 0; mi < 4; ++mi) {
    #pragma unroll
    for (int j = 0; j < 4; ++j) {
      int r = mw * 64 + mi * 16 + q * 4 + j;
      if (r < rows) {
        int tok = (g == 8) ? (hrow0 + r) : perm[pb + r];
        size_t ob = (size_t)tok * HIDDEN + pp2 * 256 + nw * 64;
        #pragma unroll
        for (int ni = 0; ni < 4; ++ni)
          dstb[ob + ni * 16 + rl] = acc[mi][ni][j];
      }
    }
  }
}

__global__ void k_add(float* __restrict__ out, const float* __restrict__ yexp, int n4) {
  int i = blockIdx.x * blockDim.x + threadIdx.x;
  if (i >= n4) return;
  float4 a = ((const float4*)out)[i];
  float4 b = ((const float4*)yexp)[i];
  a.x += b.x; a.y += b.y; a.z += b.z; a.w += b.w;
  ((float4*)out)[i] = a;
}

// ---------------- launcher ----------------

extern "C" void kernel_launch(void* const* d_in, const int* in_sizes, int n_in,
                              void* d_out, int out_size, void* d_ws, size_t ws_size,
                              hipStream_t stream) {
  const float* x   = (const float*)d_in[0];
  const float* w1s = (const float*)d_in[1];
  const float* w2s = (const float*)d_in[2];
  const float* w3s = (const float*)d_in[3];
  const float* W1  = (const float*)d_in[4];
  const float* W2  = (const float*)d_in[5];
  const float* W3  = (const float*)d_in[6];
  const float* Wg  = (const float*)d_in[7];
  float* out = (float*)d_out;

  char* ws = (char*)d_ws;
  size_t o_xb   = 0;
  size_t o_H    = o_xb   + (size_t)NTOK * HIDDEN * 2;           // 8 MB
  size_t o_yexp = o_H    + (size_t)HROWS * INTER * 2;           // +64 MB
  size_t o_Wb   = o_yexp + (size_t)NTOK * HIDDEN * 4;           // +16 MB
  size_t o_idx  = o_Wb   + (size_t)NMAT * 1024 * 8192;          // +216 MB
  size_t o_perm = o_idx  + (size_t)NTOK * 4;
  size_t o_cnt  = o_perm + (size_t)NTOK * 4;
  size_t o_off  = o_cnt  + 32;
  size_t o_fill = o_off  + 32;
  size_t o_nb1  = o_fill + 32;
  size_t o_nb2  = o_nb1  + 32;
  size_t o_tab1 = o_nb2  + 32;
  size_t o_tab2 = o_tab1 + (size_t)MAXB1 * 16;
  size_t need   = o_tab2 + (size_t)MAXB2 * 16;
  if (ws_size < need) return;  // insufficient scratch

  u16*  xb   = (u16*)(ws + o_xb);
  u16*  Hbuf = (u16*)(ws + o_H);
  float* yexp = (float*)(ws + o_yexp);
  u16*  Wb   = (u16*)(ws + o_Wb);
  int*  idx  = (int*)(ws + o_idx);
  int*  perm = (int*)(ws + o_perm);
  int*  cnt  = (int*)(ws + o_cnt);
  int*  off  = (int*)(ws + o_off);
  int*  fill = (int*)(ws + o_fill);
  int*  nblk1 = (int*)(ws + o_nb1);
  int*  nblk2 = (int*)(ws + o_nb2);
  int4* tab1 = (int4*)(ws + o_tab1);
  int4* tab2 = (int4*)(ws + o_tab2);

  k_init<<<1, 64, 0, stream>>>(cnt, fill);
  k_gate<<<NTOK / 4, 256, 0, stream>>>(x, Wg, idx, cnt);
  k_cvt<<<(NTOK * HIDDEN / 4) / 256, 256, 0, stream>>>(x, xb, NTOK * HIDDEN / 4);
  k_wcvt<<<NMAT * 512, 256, 0, stream>>>(w1s, w2s, w3s, W1, W2, W3, Wb);
  k_table<<<1, 1, 0, stream>>>(cnt, off, tab1, nblk1, tab2, nblk2);
  k_scatter<<<NTOK / 256, 256, 0, stream>>>(idx, off, fill, perm);
  k_mlp1<<<dim3(MAXB1, INTER / 128), 512, 131072, stream>>>(xb, Wb, perm, tab1, nblk1, Hbuf);
  k_mlp2<<<dim3(MAXB2, HIDDEN / 256), 512, 98304, stream>>>(Hbuf, Wb, perm, tab2, nblk2, out, yexp);
  k_add<<<(NTOK * HIDDEN / 4) / 256, 256, 0, stream>>>(out, yexp, NTOK * HIDDEN / 4);
}